// Round 1
// baseline (473.699 us; speedup 1.0000x reference)
//
#include <hip/hip_runtime.h>
#include <math.h>

#define IN_CHAN 4096
#define BATCH   16
#define KS      8              // k-split factor for the QKV GEMM
#define KC      (IN_CHAN / KS) // 512 k per block-wave

#if __has_builtin(__builtin_amdgcn_exp2f)
#define EXP2F(x) __builtin_amdgcn_exp2f(x)
#else
#define EXP2F(x) exp2f(x)
#endif

// ---------------------------------------------------------------------------
// K1: partial QKV GEMV.  partial[ks][mat][b][i] = sum_{k in chunk} W[i][k]*x[b][k]
// One wave per block. Lane l owns output row i = itile*64 + l; k is uniform
// across the wave so x[b][k] goes through the scalar pipe (SGPR operand FMAs).
// W is streamed per-lane in full 64B lines (16 floats per unrolled iter).
// ---------------------------------------------------------------------------
__global__ __launch_bounds__(64) void k_qkv_partial(
    const float* __restrict__ x,
    const float* __restrict__ wq,
    const float* __restrict__ wk,
    const float* __restrict__ wv,
    float* __restrict__ partial)
{
    const int bx    = blockIdx.x;
    const int ks    = bx & (KS - 1);
    const int itile = (bx >> 3) & 63;
    const int mat   = bx >> 9;          // 0=q, 1=k, 2=v
    const float* __restrict__ W = (mat == 0) ? wq : (mat == 1) ? wk : wv;

    const int lane = threadIdx.x;
    const int i    = itile * 64 + lane;
    const int k0   = ks * KC;

    float acc[BATCH];
#pragma unroll
    for (int b = 0; b < BATCH; ++b) acc[b] = 0.f;

    const float4* __restrict__ Wrow =
        reinterpret_cast<const float4*>(W + (size_t)i * IN_CHAN + k0);

    for (int kt = 0; kt < KC; kt += 16) {
        float w[16];
#pragma unroll
        for (int q4 = 0; q4 < 4; ++q4) {
            float4 t = Wrow[(kt >> 2) + q4];
            w[q4 * 4 + 0] = t.x;
            w[q4 * 4 + 1] = t.y;
            w[q4 * 4 + 2] = t.z;
            w[q4 * 4 + 3] = t.w;
        }
#pragma unroll
        for (int b = 0; b < BATCH; ++b) {
            const float* __restrict__ xb = x + b * IN_CHAN + k0 + kt; // uniform addr
            float a = acc[b];
#pragma unroll
            for (int kk = 0; kk < 16; ++kk) a = fmaf(w[kk], xb[kk], a);
            acc[b] = a;
        }
    }

    const size_t base = ((size_t)ks * 3 + mat) * BATCH * IN_CHAN;
#pragma unroll
    for (int b = 0; b < BATCH; ++b)
        partial[base + (size_t)b * IN_CHAN + i] = acc[b];
}

// ---------------------------------------------------------------------------
// K1b: reduce KS partials, add bias, pre-scale k by log2(e).
// qkv layout: [mat][b][i], mat 0=q, 1=k*log2e, 2=v
// ---------------------------------------------------------------------------
__global__ __launch_bounds__(256) void k_qkv_reduce(
    const float* __restrict__ partial,
    const float* __restrict__ bq,
    const float* __restrict__ bk,
    const float* __restrict__ bv,
    float* __restrict__ qkv)
{
    const int f = blockIdx.x * 256 + threadIdx.x; // 0 .. 3*16*4096-1
    float s = 0.f;
#pragma unroll
    for (int p = 0; p < KS; ++p)
        s += partial[(size_t)p * (3 * BATCH * IN_CHAN) + f];

    const int mat = f >> 16;          // 65536 elements per matrix
    const int i   = f & (IN_CHAN - 1);
    const float bias = (mat == 0) ? bq[i] : (mat == 1) ? bk[i] : bv[i];
    s += bias;
    if (mat == 1) s *= 1.44269504088896340736f; // log2(e)
    qkv[f] = s;
}

// ---------------------------------------------------------------------------
// K2: rank-1 attention.  out[b,i] = sum_j exp(q_i*k_j)*v_j / sum_j exp(q_i*k_j)
// One thread per (b,i). j uniform across wave -> k2/v via scalar loads.
// exp(q*k) = exp2(q * (k*log2e)) -> native v_exp_f32.
// 4-way partial accumulators limit fp32 summation error.
// ---------------------------------------------------------------------------
__global__ __launch_bounds__(256) void k_attn(
    const float* __restrict__ qkv,
    float* __restrict__ out)
{
    const int bx = blockIdx.x;
    const int b  = bx >> 4;
    const int i  = (bx & 15) * 256 + threadIdx.x;

    const float* __restrict__ k2 = qkv + (size_t)(1 * BATCH + b) * IN_CHAN;
    const float* __restrict__ v  = qkv + (size_t)(2 * BATCH + b) * IN_CHAN;
    const float q = qkv[(size_t)b * IN_CHAN + i];

    float num0 = 0.f, num1 = 0.f, num2 = 0.f, num3 = 0.f;
    float den0 = 0.f, den1 = 0.f, den2 = 0.f, den3 = 0.f;

    for (int j = 0; j < IN_CHAN; j += 8) {
        float e0 = EXP2F(q * k2[j + 0]);
        float e1 = EXP2F(q * k2[j + 1]);
        float e2 = EXP2F(q * k2[j + 2]);
        float e3 = EXP2F(q * k2[j + 3]);
        float e4 = EXP2F(q * k2[j + 4]);
        float e5 = EXP2F(q * k2[j + 5]);
        float e6 = EXP2F(q * k2[j + 6]);
        float e7 = EXP2F(q * k2[j + 7]);
        num0 = fmaf(e0, v[j + 0], num0); den0 += e0;
        num1 = fmaf(e1, v[j + 1], num1); den1 += e1;
        num2 = fmaf(e2, v[j + 2], num2); den2 += e2;
        num3 = fmaf(e3, v[j + 3], num3); den3 += e3;
        num0 = fmaf(e4, v[j + 4], num0); den0 += e4;
        num1 = fmaf(e5, v[j + 5], num1); den1 += e5;
        num2 = fmaf(e6, v[j + 6], num2); den2 += e6;
        num3 = fmaf(e7, v[j + 7], num3); den3 += e7;
    }

    const float num = (num0 + num1) + (num2 + num3);
    const float den = (den0 + den1) + (den2 + den3);
    out[(size_t)b * IN_CHAN + i] = num / den;
}

// ---------------------------------------------------------------------------
extern "C" void kernel_launch(void* const* d_in, const int* in_sizes, int n_in,
                              void* d_out, int out_size, void* d_ws, size_t ws_size,
                              hipStream_t stream)
{
    const float* x  = (const float*)d_in[0];
    const float* wq = (const float*)d_in[1];
    const float* bq = (const float*)d_in[2];
    const float* wk = (const float*)d_in[3];
    const float* bk = (const float*)d_in[4];
    const float* wv = (const float*)d_in[5];
    const float* bv = (const float*)d_in[6];
    float* out = (float*)d_out;

    float* partial = (float*)d_ws;                           // KS*3*16*4096 floats (6.3 MB)
    float* qkv     = partial + (size_t)KS * 3 * BATCH * IN_CHAN; // 3*16*4096 floats (0.79 MB)

    k_qkv_partial<<<3 * 64 * KS, 64, 0, stream>>>(x, wq, wk, wv, partial);
    k_qkv_reduce<<<(3 * BATCH * IN_CHAN) / 256, 256, 0, stream>>>(partial, bq, bk, bv, qkv);
    k_attn<<<(BATCH * IN_CHAN) / 256, 256, 0, stream>>>(qkv, out);
}

// Round 3
// 371.522 us; speedup vs baseline: 1.2750x; 1.2750x over previous
//
#include <hip/hip_runtime.h>
#include <math.h>

#define IN_CHAN 4096
#define BATCH   16
#define KSB     4                         // cross-block k-split (partial buffers)
#define WAVES   8                         // waves per K1 block (in-block k-split)
#define KW      (IN_CHAN / (KSB * WAVES)) // 128 k per wave

#if __has_builtin(__builtin_amdgcn_exp2f)
#define EXP2F(x) __builtin_amdgcn_exp2f(x)
#else
#define EXP2F(x) exp2f(x)
#endif

// ---------------------------------------------------------------------------
// K1: partial QKV GEMV, latency-optimized.
// Block = (mat, itile, ksb); 8 waves split the ksb k-range 8 ways.
// Lane l owns output row i = itile*64+l; its 512B W chunk is contiguous,
// streamed as 4 chunks of 8x float4 with double buffering (8 loads always
// in flight). x[b][k] is wave-uniform -> scalar pipe, zero vector-mem cost.
// In-block LDS reduction across the 8 waves -> only KSB=4 global partials.
// ---------------------------------------------------------------------------
__global__ __launch_bounds__(512, 4) void k_qkv_partial(
    const float* __restrict__ x,
    const float* __restrict__ wq,
    const float* __restrict__ wk,
    const float* __restrict__ wv,
    float* __restrict__ partial)
{
    const int bx    = blockIdx.x;          // 3*64*KSB = 768
    const int mat   = bx >> 8;             // 0=q, 1=k, 2=v
    const int rem   = bx & 255;
    const int itile = rem >> 2;
    const int ksb   = rem & (KSB - 1);
    const float* __restrict__ W = (mat == 0) ? wq : (mat == 1) ? wk : wv;

    const int wave = threadIdx.x >> 6;
    const int lane = threadIdx.x & 63;
    const int i    = itile * 64 + lane;
    const int k0   = (ksb * WAVES + wave) * KW;

    const float4* __restrict__ Wrow =
        reinterpret_cast<const float4*>(W + (size_t)i * IN_CHAN + k0);

    float acc[BATCH];
#pragma unroll
    for (int b = 0; b < BATCH; ++b) acc[b] = 0.f;

    float4 A[8], Bv[8];
#pragma unroll
    for (int t = 0; t < 8; ++t) A[t] = Wrow[t];        // chunk 0 in flight
#pragma unroll
    for (int t = 0; t < 8; ++t) Bv[t] = Wrow[8 + t];   // chunk 1 in flight

    auto compute = [&](const float4* wbuf, int c) {
        const float* __restrict__ xb = x + k0 + c * 32; // wave-uniform base
#pragma unroll
        for (int b = 0; b < BATCH; ++b) {
            const float* __restrict__ xp = xb + b * IN_CHAN;
            float a = acc[b];
#pragma unroll
            for (int t = 0; t < 8; ++t) {
                a = fmaf(wbuf[t].x, xp[t * 4 + 0], a);
                a = fmaf(wbuf[t].y, xp[t * 4 + 1], a);
                a = fmaf(wbuf[t].z, xp[t * 4 + 2], a);
                a = fmaf(wbuf[t].w, xp[t * 4 + 3], a);
            }
            acc[b] = a;
        }
    };

    compute(A, 0);
#pragma unroll
    for (int t = 0; t < 8; ++t) A[t] = Wrow[16 + t];   // chunk 2 in flight
    compute(Bv, 1);
#pragma unroll
    for (int t = 0; t < 8; ++t) Bv[t] = Wrow[24 + t];  // chunk 3 in flight
    compute(A, 2);
    compute(Bv, 3);

    // in-block reduction across 8 waves
    __shared__ float red[WAVES][BATCH][64];
#pragma unroll
    for (int b = 0; b < BATCH; ++b) red[wave][b][lane] = acc[b];
    __syncthreads();

    const int tb = threadIdx.x >> 6; // 0..7, reuse as batch index
#pragma unroll
    for (int half = 0; half < 2; ++half) {
        const int b = tb + half * 8;
        float s = 0.f;
#pragma unroll
        for (int w = 0; w < WAVES; ++w) s += red[w][b][lane];
        partial[(((size_t)ksb * 3 + mat) * BATCH + b) * IN_CHAN + i] = s;
    }
}

// ---------------------------------------------------------------------------
// K1b: reduce KSB partials, add bias, pre-scale k by log2(e).
// qkv layout: [mat][b][i], mat 0=q, 1=k*log2e, 2=v
// ---------------------------------------------------------------------------
__global__ __launch_bounds__(256) void k_qkv_reduce(
    const float* __restrict__ partial,
    const float* __restrict__ bq,
    const float* __restrict__ bk,
    const float* __restrict__ bv,
    float* __restrict__ qkv)
{
    const int f = blockIdx.x * 256 + threadIdx.x; // 0 .. 3*16*4096-1
    float s = 0.f;
#pragma unroll
    for (int p = 0; p < KSB; ++p)
        s += partial[(size_t)p * (3 * BATCH * IN_CHAN) + f];

    const int mat = f >> 16;          // 65536 elements per matrix
    const int i   = f & (IN_CHAN - 1);
    const float bias = (mat == 0) ? bq[i] : (mat == 1) ? bk[i] : bv[i];
    s += bias;
    if (mat == 1) s *= 1.44269504088896340736f; // log2(e)
    qkv[f] = s;
}

// ---------------------------------------------------------------------------
// K2: rank-1 attention.  out[b,i] = sum_j exp(q_i*k_j)*v_j / sum_j exp(q_i*k_j)
// Block = (b, itile of 64 i's); 4 waves split j 4 ways; LDS-reduce num/den.
// j is wave-uniform -> k2/v via scalar loads. exp via native v_exp_f32.
// ---------------------------------------------------------------------------
__global__ __launch_bounds__(256) void k_attn(
    const float* __restrict__ qkv,
    float* __restrict__ out)
{
    const int b     = blockIdx.x >> 6;   // 16
    const int itile = blockIdx.x & 63;   // 64
    const int wave  = threadIdx.x >> 6;  // 4
    const int lane  = threadIdx.x & 63;
    const int i     = itile * 64 + lane;

    const float* __restrict__ k2 = qkv + (size_t)(BATCH + b) * IN_CHAN;
    const float* __restrict__ v  = qkv + (size_t)(2 * BATCH + b) * IN_CHAN;
    const float q = qkv[(size_t)b * IN_CHAN + i];

    float num0 = 0.f, num1 = 0.f, num2 = 0.f, num3 = 0.f;
    float den0 = 0.f, den1 = 0.f, den2 = 0.f, den3 = 0.f;

    const int j0 = wave * (IN_CHAN / 4);
    for (int j = j0; j < j0 + IN_CHAN / 4; j += 8) {
        float e0 = EXP2F(q * k2[j + 0]);
        float e1 = EXP2F(q * k2[j + 1]);
        float e2 = EXP2F(q * k2[j + 2]);
        float e3 = EXP2F(q * k2[j + 3]);
        float e4 = EXP2F(q * k2[j + 4]);
        float e5 = EXP2F(q * k2[j + 5]);
        float e6 = EXP2F(q * k2[j + 6]);
        float e7 = EXP2F(q * k2[j + 7]);
        num0 = fmaf(e0, v[j + 0], num0); den0 += e0;
        num1 = fmaf(e1, v[j + 1], num1); den1 += e1;
        num2 = fmaf(e2, v[j + 2], num2); den2 += e2;
        num3 = fmaf(e3, v[j + 3], num3); den3 += e3;
        num0 = fmaf(e4, v[j + 4], num0); den0 += e4;
        num1 = fmaf(e5, v[j + 5], num1); den1 += e5;
        num2 = fmaf(e6, v[j + 6], num2); den2 += e6;
        num3 = fmaf(e7, v[j + 7], num3); den3 += e7;
    }

    const float num = (num0 + num1) + (num2 + num3);
    const float den = (den0 + den1) + (den2 + den3);

    __shared__ float red[2][4][64];
    red[0][wave][lane] = num;
    red[1][wave][lane] = den;
    __syncthreads();
    if (wave == 0) {
        const float n = (red[0][0][lane] + red[0][1][lane]) +
                        (red[0][2][lane] + red[0][3][lane]);
        const float d = (red[1][0][lane] + red[1][1][lane]) +
                        (red[1][2][lane] + red[1][3][lane]);
        out[(size_t)b * IN_CHAN + i] = n / d;
    }
}

// ---------------------------------------------------------------------------
extern "C" void kernel_launch(void* const* d_in, const int* in_sizes, int n_in,
                              void* d_out, int out_size, void* d_ws, size_t ws_size,
                              hipStream_t stream)
{
    const float* x  = (const float*)d_in[0];
    const float* wq = (const float*)d_in[1];
    const float* bq = (const float*)d_in[2];
    const float* wk = (const float*)d_in[3];
    const float* bk = (const float*)d_in[4];
    const float* wv = (const float*)d_in[5];
    const float* bv = (const float*)d_in[6];
    float* out = (float*)d_out;

    float* partial = (float*)d_ws;                               // 3.1 MB
    float* qkv     = partial + (size_t)KSB * 3 * BATCH * IN_CHAN; // 0.79 MB

    k_qkv_partial<<<3 * 64 * KSB, 512, 0, stream>>>(x, wq, wk, wv, partial);
    k_qkv_reduce<<<(3 * BATCH * IN_CHAN) / 256, 256, 0, stream>>>(partial, bq, bk, bv, qkv);
    k_attn<<<BATCH * 64, 256, 0, stream>>>(qkv, out);
}